// Round 5
// baseline (187.987 us; speedup 1.0000x reference)
//
#include <hip/hip_runtime.h>

// ---------------------------------------------------------------------------
// MultiHeadSelfAttention: B=2, S=2048, D=1024, H=16, HD=64, fp32 in/out.
// prep (cast X + transpose W) -> 3-way fused QKV GEMM -> split-T flash
// attention (fixed-max softmax, 128-row Q blocks, register-P via swapped
// QK + bit-permuted K staging) -> combine -> out GEMM.
// mfma_f32_16x16x32_bf16, fp32 accum.
// THIS ROUND (T15): attn 2-tile register pipeline. Iter i runs
//   exp(i) | vmcnt(0)+lgkm(0)+barrier | stage(i+2) | QK(i+1) | PV(i)
// so exp(i) VALU overlaps PV(i-1)'s draining MFMAs (within-wave MFMA/VALU
// overlap) and staging leads consumption by a full iteration (~1700 cyc).
// Buffers: K x2, V x3 (stage(i+2) overwrite target must be one-barrier-old:
// K(i) read by QK(i) pre-barrier; V slot holds V(i-1), read by PV(i-1)).
// sf is double-banked STATICALLY (sfA/sfB, loop unrolled x2); exp fused into
// cvt_pk (no pe array) to keep VGPR <= 128 (4 blocks/CU at 40.9 KB LDS).
// XOR swizzle: LDS rows are 64 shorts (128 B); chunk c (16 B) of row r holds
// global chunk c^(r&7). Staging permutes the GLOBAL address (global_load_lds
// dest must be base+lane*16); fragment reads apply the same permutation.
// ---------------------------------------------------------------------------

typedef __bf16 bf16x8 __attribute__((ext_vector_type(8)));
typedef float  f32x4  __attribute__((ext_vector_type(4)));

#if __has_builtin(__builtin_amdgcn_exp2f)
#define EXPFN(x) __builtin_amdgcn_exp2f(x)
#define QSCALE (0.125f * 1.44269504088896f)   // fold log2(e) into Q
#else
#define EXPFN(x) __expf(x)
#define QSCALE 0.125f
#endif

#define VMCNT(n)  asm volatile("s_waitcnt vmcnt(" #n ")" ::: "memory")
#define LGKMCNT0() asm volatile("s_waitcnt lgkmcnt(0)" ::: "memory")
#define BARRIER() __builtin_amdgcn_s_barrier()
#define WAIT0_BARRIER() asm volatile("s_waitcnt vmcnt(0)\n\ts_barrier" ::: "memory")

__device__ __forceinline__ unsigned short f2bf(float f) {
    unsigned int u = __float_as_uint(f);
    u += 0x7FFFu + ((u >> 16) & 1u);   // RNE; finite inputs
    return (unsigned short)(u >> 16);
}

// async global->LDS, 16B per lane; HW dest = firstlane(lptr) + lane*16.
__device__ __forceinline__ void gload16(const void* g, void* l) {
    __builtin_amdgcn_global_load_lds(
        (const __attribute__((address_space(1))) void*)g,
        (__attribute__((address_space(3))) void*)l, 16, 0, 0);
}

// ---------------- prep: cast X (z=4) + transpose/cast W (z=0..3) -----------
__global__ __launch_bounds__(256) void prep_kernel(
    const float* __restrict__ X, ushort4* __restrict__ Xb,
    const float* __restrict__ Wq, const float* __restrict__ Wk,
    const float* __restrict__ Wv, const float* __restrict__ Wo,
    unsigned short* __restrict__ Wt_all) {
    const int z = blockIdx.z;
    if (z == 4) {
        int base = (blockIdx.y * 32 + blockIdx.x) * 1024 + threadIdx.x;
        const float4* X4 = (const float4*)X;
        #pragma unroll
        for (int c = 0; c < 4; c++) {
            int i = base + c * 256;
            float4 v = X4[i];
            ushort4 o;
            o.x = f2bf(v.x); o.y = f2bf(v.y); o.z = f2bf(v.z); o.w = f2bf(v.w);
            Xb[i] = o;
        }
        return;
    }
    __shared__ float tile[32][33];
    const float* W = (z == 0) ? Wq : (z == 1) ? Wk : (z == 2) ? Wv : Wo;
    unsigned short* Wt = Wt_all + (size_t)z * 1024 * 1024;
    int c0 = blockIdx.x * 32, r0 = blockIdx.y * 32;
    int x = threadIdx.x & 31, y = threadIdx.x >> 5;   // (32, 8)
    for (int j = 0; j < 32; j += 8)
        tile[y + j][x] = W[(r0 + y + j) * 1024 + c0 + x];
    __syncthreads();
    for (int j = 0; j < 32; j += 8)
        Wt[(c0 + y + j) * 1024 + r0 + x] = f2bf(tile[x][y + j]);
}

// ---------------- 3-way fused QKV GEMM (128x64 tile, BK=64) ----------------
// Per block: As = X rows [x0,x0+128) staged once; Bq/Bk/Bv = W rows
// [y0,y0+64). 48 MFMA / 10 gloads per iter. Grid (32,16) = 512 = 2/CU.
// Q -> Qb[B,H,S,64] (scaled), K -> Kb[B,H,S,64], V -> Vt[B,H,64,S] via
// epilogue LDS transpose (stride 136 shorts: 16B-aligned rows, 2-way banks).
__global__ __launch_bounds__(256, 2) void gemm_qkv_kernel(
    const unsigned short* __restrict__ Xb, const unsigned short* __restrict__ Wt_all,
    const float* __restrict__ bq, const float* __restrict__ bk,
    const float* __restrict__ bv,
    unsigned short* __restrict__ Qb, unsigned short* __restrict__ Kb,
    unsigned short* __restrict__ Vt) {
    const int x0 = blockIdx.x * 128;   // over 4096 (X rows / seq)
    const int y0 = blockIdx.y * 64;    // over 1024 (W rows / out cols)

    __shared__ __align__(16) unsigned short smem[128 * 64 + 3 * 64 * 64]; // 40 KB
    unsigned short* As  = smem;             // 128x64
    unsigned short* Bqs = smem + 8192;      // 64x64
    unsigned short* Bks = smem + 12288;     // 64x64
    unsigned short* Bvs = smem + 16384;     // 64x64

    const unsigned short* Ap  = Xb + (size_t)x0 * 1024;
    const unsigned short* Bqp = Wt_all + (size_t)y0 * 1024;
    const unsigned short* Bkp = Wt_all + 1048576u + (size_t)y0 * 1024;
    const unsigned short* Bvp = Wt_all + 2097152u + (size_t)y0 * 1024;

    const int tid = threadIdx.x;
    const int lane = tid & 63, wave = tid >> 6;
    const int quad = lane >> 4, l15 = lane & 15;
    const int wrow = (wave >> 1) * 64, wcol = (wave & 1) * 32;

    f32x4 aq[4][2] = {};
    f32x4 ak[4][2] = {};
    f32x4 av[4][2] = {};

    const int srow = lane >> 3;            // 0..7
    const int ch8  = (lane & 7) * 8;       // natural chunk offset (shorts)
    const int swz  = (((lane & 7) ^ srow)) * 8;  // swizzled source chunk
    const int sw   = (l15 & 7);            // read-side row swizzle key

    for (int k0 = 0; k0 < 1024; k0 += 64) {
        #pragma unroll
        for (int c = 0; c < 4; c++) {
            int r = c * 32 + wave * 8 + srow;
            gload16(Ap + (size_t)r * 1024 + k0 + swz, &As[r * 64 + ch8]);
        }
        #pragma unroll
        for (int c = 0; c < 2; c++) {
            int r = c * 32 + wave * 8 + srow;
            gload16(Bqp + (size_t)r * 1024 + k0 + swz, &Bqs[r * 64 + ch8]);
            gload16(Bkp + (size_t)r * 1024 + k0 + swz, &Bks[r * 64 + ch8]);
            gload16(Bvp + (size_t)r * 1024 + k0 + swz, &Bvs[r * 64 + ch8]);
        }
        WAIT0_BARRIER();
        #pragma unroll
        for (int kk = 0; kk < 2; kk++) {
            bf16x8 af[4], bqf[2], bkf[2], bvf[2];
            const int co = (((kk * 4 + quad) ^ sw)) * 8;
            #pragma unroll
            for (int i = 0; i < 4; i++)
                af[i] = *(const bf16x8*)&As[(wrow + i * 16 + l15) * 64 + co];
            #pragma unroll
            for (int j = 0; j < 2; j++) {
                bqf[j] = *(const bf16x8*)&Bqs[(wcol + j * 16 + l15) * 64 + co];
                bkf[j] = *(const bf16x8*)&Bks[(wcol + j * 16 + l15) * 64 + co];
                bvf[j] = *(const bf16x8*)&Bvs[(wcol + j * 16 + l15) * 64 + co];
            }
            #pragma unroll
            for (int i = 0; i < 4; i++)
                #pragma unroll
                for (int j = 0; j < 2; j++) {
                    aq[i][j] = __builtin_amdgcn_mfma_f32_16x16x32_bf16(
                        af[i], bqf[j], aq[i][j], 0, 0, 0);
                    ak[i][j] = __builtin_amdgcn_mfma_f32_16x16x32_bf16(
                        af[i], bkf[j], ak[i][j], 0, 0, 0);
                    av[i][j] = __builtin_amdgcn_mfma_f32_16x16x32_bf16(
                        af[i], bvf[j], av[i][j], 0, 0, 0);
                }
        }
        __syncthreads();
    }

    // Q/K epilogue (registers only). C/D: col=lane&15, row=quad*4+reg.
    #pragma unroll
    for (int j = 0; j < 2; j++) {
        int col = y0 + wcol + j * 16 + l15;
        float bqc = bq[col], bkc = bk[col];
        int h = col >> 6, d = col & 63;
        #pragma unroll
        for (int i = 0; i < 4; i++)
            #pragma unroll
            for (int r = 0; r < 4; r++) {
                int row = x0 + wrow + i * 16 + quad * 4 + r;
                int b = row >> 11, s = row & 2047;
                size_t idx = (size_t)((b * 16 + h) * 2048 + s) * 64 + d;
                Qb[idx] = f2bf((aq[i][j][r] + bqc) * QSCALE);
                Kb[idx] = f2bf(ak[i][j][r] + bkc);
            }
    }

    // V epilogue: transpose through LDS, then coalesced V^T stores.
    __syncthreads();                        // staging smem now free
    unsigned short* vts = smem;             // 64 x 136 shorts (17.4 KB)
    #pragma unroll
    for (int j = 0; j < 2; j++) {
        int n = wcol + j * 16 + l15;        // 0..63 (d within tile)
        float bvc = bv[y0 + n];
        #pragma unroll
        for (int i = 0; i < 4; i++)
            #pragma unroll
            for (int r = 0; r < 4; r++) {
                int m = wrow + i * 16 + quad * 4 + r;   // 0..127 (seq in tile)
                vts[n * 136 + m] = f2bf(av[i][j][r] + bvc);
            }
    }
    __syncthreads();
    const int bseq = x0 >> 11;
    const int s0 = x0 & 2047;
    #pragma unroll
    for (int q = 0; q < 4; q++) {
        int c = q * 256 + tid;              // 0..1023 chunks of 16B
        int n = c >> 4, mc = c & 15;
        uint4 vv = *(const uint4*)&vts[n * 136 + mc * 8];
        *(uint4*)&Vt[(size_t)(bseq * 1024 + y0 + n) * 2048 + s0 + mc * 8] = vv;
    }
}

// ---------------- flash attention (fixed-max, split-T) ---------------------
// 128 Q rows/block, 4 waves x 32 rows (mi=2). l via MFMA ones-column.
// Register-P + 2-tile pipeline: iter i = exp(i); sync; stage(i+2);
// QK(i+1); PV(i). K x2 / V x3 LDS buffers (40.9 KB -> 4 blocks/CU).
__global__ __launch_bounds__(256) void attn_kernel(
    const unsigned short* __restrict__ Qb, const unsigned short* __restrict__ Kb,
    const unsigned short* __restrict__ Vt, unsigned short* __restrict__ Cc,
    float* __restrict__ Op, float* __restrict__ Lp, int tlen, int do_split) {
    const int bh = blockIdx.y;            // 0..31
    const int b = bh >> 4, h = bh & 15;
    const int q0 = blockIdx.x * 128;
    const int split = blockIdx.z;
    const int tbeg = split * tlen;

    const int tid = threadIdx.x;
    const int lane = tid & 63, wave = tid >> 6;
    const int quad = lane >> 4, l15 = lane & 15;

    __shared__ __align__(16) unsigned short Ks[2][64 * 64];
    __shared__ __align__(16) unsigned short Vs[3][64 * 64];

    const unsigned short* Qbh = Qb + (size_t)bh * 2048 * 64;
    const unsigned short* Kbh = Kb + (size_t)bh * 2048 * 64;
    const unsigned short* Vbh = Vt + (size_t)bh * 64 * 2048;

    // Q fragments in registers: B-operand layout n=lane&15, k=quad*8+j
    bf16x8 qa[2][2];
    #pragma unroll
    for (int mi = 0; mi < 2; mi++)
        #pragma unroll
        for (int kk = 0; kk < 2; kk++)
            qa[mi][kk] = *(const bf16x8*)&Qbh[
                (size_t)(q0 + wave * 32 + mi * 16 + l15) * 64 + kk * 32 + quad * 8];

    union { unsigned short us[8]; bf16x8 v; } ones_u;
    #pragma unroll
    for (int i = 0; i < 8; i++) ones_u.us[i] = 0x3F80;
    const bf16x8 onesv = ones_u.v;

    f32x4 o[2][4] = {};
    f32x4 ol[2] = {};

    const int srow = lane >> 3;                 // 0..7
    const int r0s = wave * 16 + srow;           // staging rows (2 per lane)
    const int ch8 = (lane & 7) * 8;
    const int swz = (((lane & 7) ^ srow)) * 8;  // row&7 == srow for both rows
    const int sw  = (l15 & 7);

    // K row bit-permutation: LDS row t' holds global K row perm(t'), with
    // t' = [kk jl q1 q0 r1 r0] <- t = [kk q1 q0 jl r1 r0]. This makes the
    // PV A-fragment k-slot equal NATURAL t (V stays unpermuted).
    const int pk0 = (r0s & 0x23) | ((r0s & 0x0C) << 1) | ((r0s & 0x10) >> 2);
    const int r8  = r0s + 8;
    const int pk8 = (r8 & 0x23) | ((r8 & 0x0C) << 1) | ((r8 & 0x10) >> 2);

    // stage tile i: K(i) -> Ks[i&1], V(i) -> Vs[i%3]
    auto stage = [&](int i) {
        const int t0 = tbeg + i * 64;
        unsigned short* Kd = Ks[i & 1];
        unsigned short* Vd = Vs[i % 3];
        gload16(&Kbh[(size_t)(t0 + pk0) * 64 + swz],       &Kd[r0s * 64 + ch8]);
        gload16(&Kbh[(size_t)(t0 + pk8) * 64 + swz],       &Kd[(r0s + 8) * 64 + ch8]);
        gload16(&Vbh[(size_t)r0s * 2048 + t0 + swz],       &Vd[r0s * 64 + ch8]);
        gload16(&Vbh[(size_t)(r0s + 8) * 2048 + t0 + swz], &Vd[(r0s + 8) * 64 + ch8]);
    };

    auto qk_tile = [&](int i, f32x4 (&sfN)[2][4]) {
        const unsigned short* Ksc = Ks[i & 1];
        #pragma unroll
        for (int mi = 0; mi < 2; mi++)
            #pragma unroll
            for (int j = 0; j < 4; j++)
                sfN[mi][j] = (f32x4){0.f, 0.f, 0.f, 0.f};
        #pragma unroll
        for (int j = 0; j < 4; j++)
            #pragma unroll
            for (int kk = 0; kk < 2; kk++) {
                bf16x8 kf = *(const bf16x8*)&Ksc[(j * 16 + l15) * 64 +
                                                 (((kk * 4 + quad) ^ sw)) * 8];
                sfN[0][j] = __builtin_amdgcn_mfma_f32_16x16x32_bf16(kf, qa[0][kk], sfN[0][j], 0, 0, 0);
                sfN[1][j] = __builtin_amdgcn_mfma_f32_16x16x32_bf16(kf, qa[1][kk], sfN[1][j], 0, 0, 0);
            }
    };

    const int NT = tlen >> 6;   // 16

    // iter i: exp(sfC->pa); sync; stage(i+2); QK(i+1)->sfN; PV(i).
    auto iter_body = [&](int i, f32x4 (&sfC)[2][4], f32x4 (&sfN)[2][4]) {
        // P = exp2(S^T), fused into cvt_pk; pa = PV A-fragments (in-register).
        union { unsigned int u[4]; bf16x8 v; } pa[2][2];
        #pragma unroll
        for (int mi = 0; mi < 2; mi++)
            #pragma unroll
            for (int kk = 0; kk < 2; kk++)
                #pragma unroll
                for (int d = 0; d < 4; d++) {
                    const int j = 2 * kk + (d >> 1);
                    const int r = 2 * (d & 1);
                    float e0 = EXPFN(sfC[mi][j][r]);
                    float e1 = EXPFN(sfC[mi][j][r + 1]);
                    unsigned int w;
                    asm("v_cvt_pk_bf16_f32 %0, %1, %2"
                        : "=v"(w) : "v"(e0), "v"(e1));
                    pa[mi][kk].u[d] = w;
                }

        VMCNT(0);      // tile i+1's 4 loads (issued iter i-1) landed
        LGKMCNT0();    // my ds reads of K(i)/V(i-1) (issued iter i-1) done
        BARRIER();     // all waves ditto; K(i+1)/V(i+1) visible block-wide

        if (i + 2 < NT) stage(i + 2);   // K->Ks[i&1] (K(i) dead), V->Vs[(i+2)%3] (V(i-1) dead)

        if (i + 1 < NT) qk_tile(i + 1, sfN);   // MFMA burst, ds_read Ks[(i+1)&1]

        // PV(i): O += P V ; l += P @ ones
        const unsigned short* Vsc = Vs[i % 3];
        #pragma unroll
        for (int kk = 0; kk < 2; kk++) {
            bf16x8 pf0 = pa[0][kk].v;
            bf16x8 pf1 = pa[1][kk].v;
            ol[0] = __builtin_amdgcn_mfma_f32_16x16x32_bf16(pf0, onesv, ol[0], 0, 0, 0);
            ol[1] = __builtin_amdgcn_mfma_f32_16x16x32_bf16(pf1, onesv, ol[1], 0, 0, 0);
            #pragma unroll
            for (int j = 0; j < 4; j++) {
                bf16x8 vf = *(const bf16x8*)&Vsc[(j * 16 + l15) * 64 +
                                                 (((kk * 4 + quad) ^ sw)) * 8];
                o[0][j] = __builtin_amdgcn_mfma_f32_16x16x32_bf16(pf0, vf, o[0][j], 0, 0, 0);
                o[1][j] = __builtin_amdgcn_mfma_f32_16x16x32_bf16(pf1, vf, o[1][j], 0, 0, 0);
            }
        }
    };

    // Prologue: K0/V0 ready; K1/V1 in flight; sfA = QK(0).
    f32x4 sfA[2][4], sfB[2][4];
    stage(0);
    VMCNT(0);
    BARRIER();
    stage(1);
    qk_tile(0, sfA);

    // Main loop, unrolled x2 for static sf banks (NT is even).
    for (int ti = 0; ti < tlen; ti += 128) {
        const int i = ti >> 6;
        iter_body(i,     sfA, sfB);
        iter_body(i + 1, sfB, sfA);
    }

    if (do_split) {
        float* Opd = Op + (size_t)(split * 32 + bh) * 2048 * 64;
        float* Lpd = Lp + (size_t)(split * 32 + bh) * 2048;
        #pragma unroll
        for (int mi = 0; mi < 2; mi++)
            #pragma unroll
            for (int r = 0; r < 4; r++) {
                int s = q0 + wave * 32 + mi * 16 + quad * 4 + r;
                if (l15 == 0) Lpd[s] = ol[mi][r];
                #pragma unroll
                for (int j = 0; j < 4; j++)
                    Opd[(size_t)s * 64 + j * 16 + l15] = o[mi][j][r];
            }
    } else {
        #pragma unroll
        for (int mi = 0; mi < 2; mi++)
            #pragma unroll
            for (int r = 0; r < 4; r++) {
                float inv = 1.f / ol[mi][r];
                int s = q0 + wave * 32 + mi * 16 + quad * 4 + r;
                size_t row = (size_t)(b * 2048 + s);
                #pragma unroll
                for (int j = 0; j < 4; j++)
                    Cc[row * 1024 + h * 64 + j * 16 + l15] = f2bf(o[mi][j][r] * inv);
            }
    }
}

// ---------------- combine split partials -> Cc bf16 ------------------------
__global__ __launch_bounds__(256) void combine_kernel(
    const float4* __restrict__ Op, const float* __restrict__ Lp,
    unsigned short* __restrict__ Cc) {
    int idx = blockIdx.x * 256 + threadIdx.x;       // 0 .. 32*2048*16-1
    int d4 = idx & 15;
    int s = (idx >> 4) & 2047;
    int bh = idx >> 15;
    const size_t half4 = (size_t)32 * 2048 * 16;
    float4 a = Op[(size_t)idx], c = Op[half4 + (size_t)idx];
    float l = Lp[bh * 2048 + s] + Lp[32 * 2048 + bh * 2048 + s];
    float inv = 1.f / l;
    ushort4 o;
    o.x = f2bf((a.x + c.x) * inv); o.y = f2bf((a.y + c.y) * inv);
    o.z = f2bf((a.z + c.z) * inv); o.w = f2bf((a.w + c.w) * inv);
    int b = bh >> 4, h = bh & 15;
    *(ushort4*)&Cc[((size_t)(b * 2048 + s)) * 1024 + h * 64 + d4 * 4] = o;
}

// ---------------- output projection (128x64 tile, single-buffer) -----------
// grid (32,16) = 512 blocks = 2/CU; LDS 24 KB; wave tile 64x32.
__global__ __launch_bounds__(256) void gemm_out_kernel(
    const unsigned short* __restrict__ Cc, const unsigned short* __restrict__ Wot,
    const float* __restrict__ bo, float* __restrict__ out) {
    const int m0 = blockIdx.x * 128;   // over 4096
    const int n0 = blockIdx.y * 64;    // over 1024

    __shared__ __align__(16) unsigned short As[128 * 64];
    __shared__ __align__(16) unsigned short Bs[64 * 64];

    const int tid = threadIdx.x;
    const int lane = tid & 63, wave = tid >> 6;
    const int quad = lane >> 4, l15 = lane & 15;
    const int wrow = (wave >> 1) * 64, wcol = (wave & 1) * 32;

    f32x4 acc[4][2] = {};
    const int srow = lane >> 3;
    const int ch8 = (lane & 7) * 8;
    const int swz = (((lane & 7) ^ srow)) * 8;
    const int sw  = (l15 & 7);

    for (int k0 = 0; k0 < 1024; k0 += 64) {
        #pragma unroll
        for (int c = 0; c < 4; c++) {
            int r = c * 32 + wave * 8 + srow;
            gload16(Cc + (size_t)(m0 + r) * 1024 + k0 + swz, &As[r * 64 + ch8]);
            if (c < 2)
                gload16(Wot + (size_t)(n0 + r) * 1024 + k0 + swz, &Bs[r * 64 + ch8]);
        }
        WAIT0_BARRIER();
        #pragma unroll
        for (int kk = 0; kk < 2; kk++) {
            bf16x8 af[4], bfr[2];
            #pragma unroll
            for (int i = 0; i < 4; i++)
                af[i] = *(const bf16x8*)&As[(wrow + i * 16 + l15) * 64 +
                                            (((kk * 4 + quad) ^ sw)) * 8];
            #pragma unroll
            for (int j = 0; j < 2; j++)
                bfr[j] = *(const bf16x8*)&Bs[(wcol + j * 16 + l15) * 64 +
                                             (((kk * 4 + quad) ^ sw)) * 8];
            #pragma unroll
            for (int i = 0; i < 4; i++)
                #pragma unroll
                for (int j = 0; j < 2; j++)
                    acc[i][j] = __builtin_amdgcn_mfma_f32_16x16x32_bf16(
                        af[i], bfr[j], acc[i][j], 0, 0, 0);
        }
        __syncthreads();
    }

    #pragma unroll
    for (int j = 0; j < 2; j++) {
        int col = n0 + wcol + j * 16 + l15;
        float bcol = bo[col];
        #pragma unroll
        for (int i = 0; i < 4; i++)
            #pragma unroll
            for (int r = 0; r < 4; r++) {
                int row = m0 + wrow + i * 16 + quad * 4 + r;
                out[(size_t)row * 1024 + col] = acc[i][j][r] + bcol;
            }
    }
}

// ---------------------------------------------------------------------------
extern "C" void kernel_launch(void* const* d_in, const int* in_sizes, int n_in,
                              void* d_out, int out_size, void* d_ws, size_t ws_size,
                              hipStream_t stream) {
    const float* X  = (const float*)d_in[0];
    const float* Wq = (const float*)d_in[1];
    const float* bq = (const float*)d_in[2];
    const float* Wk = (const float*)d_in[3];
    const float* bk = (const float*)d_in[4];
    const float* Wv = (const float*)d_in[5];
    const float* bv = (const float*)d_in[6];
    const float* Wo = (const float*)d_in[7];
    const float* bo = (const float*)d_in[8];
    float* out = (float*)d_out;

    char* ws = (char*)d_ws;
    unsigned short* Xb = (unsigned short*)(ws);                    //  8 MB
    unsigned short* Wt = (unsigned short*)(ws + (8u  << 20));      //  8 MB (4 mats)
    unsigned short* Qb = (unsigned short*)(ws + (16u << 20));      //  8 MB
    unsigned short* Kb = (unsigned short*)(ws + (24u << 20));      //  8 MB
    unsigned short* Vt = (unsigned short*)(ws + (32u << 20));      //  8 MB
    unsigned short* Cc = (unsigned short*)(ws + (40u << 20));      //  8 MB
    float* Op = (float*)(ws + (48u << 20));                        // 32 MB
    float* Lp = (float*)(ws + (48u << 20) + 33554432u);            // 512 KB
    const bool use_split = ws_size >= ((size_t)(48u << 20) + 33554432u + 524288u);

    prep_kernel<<<dim3(32, 32, 5), 256, 0, stream>>>(X, (ushort4*)Xb, Wq, Wk, Wv, Wo, Wt);
    gemm_qkv_kernel<<<dim3(32, 16), 256, 0, stream>>>(Xb, Wt, bq, bk, bv, Qb, Kb, Vt);
    if (use_split) {
        attn_kernel<<<dim3(16, 32, 2), 256, 0, stream>>>(Qb, Kb, Vt, Cc, Op, Lp, 1024, 1);
        combine_kernel<<<4096, 256, 0, stream>>>((const float4*)Op, Lp, Cc);
    } else {
        attn_kernel<<<dim3(16, 32, 1), 256, 0, stream>>>(Qb, Kb, Vt, Cc, Op, Lp, 2048, 0);
    }
    gemm_out_kernel<<<dim3(32, 16), 256, 0, stream>>>(Cc, Wt + 3u * 1024 * 1024, bo, out);
}

// Round 6
// 180.477 us; speedup vs baseline: 1.0416x; 1.0416x over previous
//
#include <hip/hip_runtime.h>

// ---------------------------------------------------------------------------
// MultiHeadSelfAttention: B=2, S=2048, D=1024, H=16, HD=64, fp32 in/out.
// prep (cast X + transpose W) -> 3-way fused QKV GEMM -> split-T flash
// attention (fixed-max softmax, 128-row Q blocks, register-P via swapped
// QK + bit-permuted K staging) -> combine -> out GEMM.
// mfma_f32_16x16x32_bf16, fp32 accum.
// THIS ROUND: attn reverted to R4 form (R5's 2-tile pipeline cost VGPR
// 64->108, occupancy 28->17%, +5.5 us — reverted). Both GEMMs now use the
// R4-proven single-barrier counted-prefetch loop:
//   vmcnt(0); lgkm(0); barrier; stage(next -> buf^1); compute(buf)
// Next tile's loads fly under the whole compute phase. Zero occupancy cost:
// qkv 2x40=80 KB -> 2 blocks/CU (== its grid cap 512/256); out 2x24=48 KB ->
// 3/CU capacity >= grid cap 2/CU. (R2 comment claiming out-dbuf halved
// occupancy was wrong — grid caps at 2/CU regardless.)
// XOR swizzle: LDS rows are 64 shorts (128 B); chunk c (16 B) of row r holds
// global chunk c^(r&7). Staging permutes the GLOBAL address (global_load_lds
// dest must be base+lane*16); fragment reads apply the same permutation.
// ---------------------------------------------------------------------------

typedef __bf16 bf16x8 __attribute__((ext_vector_type(8)));
typedef float  f32x4  __attribute__((ext_vector_type(4)));

#if __has_builtin(__builtin_amdgcn_exp2f)
#define EXPFN(x) __builtin_amdgcn_exp2f(x)
#define QSCALE (0.125f * 1.44269504088896f)   // fold log2(e) into Q
#else
#define EXPFN(x) __expf(x)
#define QSCALE 0.125f
#endif

#define VMCNT(n)  asm volatile("s_waitcnt vmcnt(" #n ")" ::: "memory")
#define LGKMCNT0() asm volatile("s_waitcnt lgkmcnt(0)" ::: "memory")
#define BARRIER() __builtin_amdgcn_s_barrier()

__device__ __forceinline__ unsigned short f2bf(float f) {
    unsigned int u = __float_as_uint(f);
    u += 0x7FFFu + ((u >> 16) & 1u);   // RNE; finite inputs
    return (unsigned short)(u >> 16);
}

// async global->LDS, 16B per lane; HW dest = firstlane(lptr) + lane*16.
__device__ __forceinline__ void gload16(const void* g, void* l) {
    __builtin_amdgcn_global_load_lds(
        (const __attribute__((address_space(1))) void*)g,
        (__attribute__((address_space(3))) void*)l, 16, 0, 0);
}

// ---------------- prep: cast X (z=4) + transpose/cast W (z=0..3) -----------
__global__ __launch_bounds__(256) void prep_kernel(
    const float* __restrict__ X, ushort4* __restrict__ Xb,
    const float* __restrict__ Wq, const float* __restrict__ Wk,
    const float* __restrict__ Wv, const float* __restrict__ Wo,
    unsigned short* __restrict__ Wt_all) {
    const int z = blockIdx.z;
    if (z == 4) {
        int base = (blockIdx.y * 32 + blockIdx.x) * 1024 + threadIdx.x;
        const float4* X4 = (const float4*)X;
        #pragma unroll
        for (int c = 0; c < 4; c++) {
            int i = base + c * 256;
            float4 v = X4[i];
            ushort4 o;
            o.x = f2bf(v.x); o.y = f2bf(v.y); o.z = f2bf(v.z); o.w = f2bf(v.w);
            Xb[i] = o;
        }
        return;
    }
    __shared__ float tile[32][33];
    const float* W = (z == 0) ? Wq : (z == 1) ? Wk : (z == 2) ? Wv : Wo;
    unsigned short* Wt = Wt_all + (size_t)z * 1024 * 1024;
    int c0 = blockIdx.x * 32, r0 = blockIdx.y * 32;
    int x = threadIdx.x & 31, y = threadIdx.x >> 5;   // (32, 8)
    for (int j = 0; j < 32; j += 8)
        tile[y + j][x] = W[(r0 + y + j) * 1024 + c0 + x];
    __syncthreads();
    for (int j = 0; j < 32; j += 8)
        Wt[(c0 + y + j) * 1024 + r0 + x] = f2bf(tile[x][y + j]);
}

// ---------------- 3-way fused QKV GEMM (128x64 tile, BK=64) ----------------
// Double-buffered (2x40 KB = 80 KB, 2 blocks/CU == grid cap). Per iter:
// vmcnt(0)+lgkm(0)+barrier, stage next tile (10 gloads/wave, full compute
// phase of cover), 48 MFMA. Grid (32,16) = 512.
// Q -> Qb[B,H,S,64] (scaled), K -> Kb[B,H,S,64], V -> Vt[B,H,64,S] via
// epilogue LDS transpose (stride 136 shorts: 16B-aligned rows, 2-way banks).
__global__ __launch_bounds__(256, 2) void gemm_qkv_kernel(
    const unsigned short* __restrict__ Xb, const unsigned short* __restrict__ Wt_all,
    const float* __restrict__ bq, const float* __restrict__ bk,
    const float* __restrict__ bv,
    unsigned short* __restrict__ Qb, unsigned short* __restrict__ Kb,
    unsigned short* __restrict__ Vt) {
    const int x0 = blockIdx.x * 128;   // over 4096 (X rows / seq)
    const int y0 = blockIdx.y * 64;    // over 1024 (W rows / out cols)

    // [buf][ As 128x64 | Bqs 64x64 | Bks 64x64 | Bvs 64x64 ]
    __shared__ __align__(16) unsigned short smem[2][20480]; // 80 KB

    const unsigned short* Ap  = Xb + (size_t)x0 * 1024;
    const unsigned short* Bqp = Wt_all + (size_t)y0 * 1024;
    const unsigned short* Bkp = Wt_all + 1048576u + (size_t)y0 * 1024;
    const unsigned short* Bvp = Wt_all + 2097152u + (size_t)y0 * 1024;

    const int tid = threadIdx.x;
    const int lane = tid & 63, wave = tid >> 6;
    const int quad = lane >> 4, l15 = lane & 15;
    const int wrow = (wave >> 1) * 64, wcol = (wave & 1) * 32;

    f32x4 aq[4][2] = {};
    f32x4 ak[4][2] = {};
    f32x4 av[4][2] = {};

    const int srow = lane >> 3;            // 0..7
    const int ch8  = (lane & 7) * 8;       // natural chunk offset (shorts)
    const int swz  = (((lane & 7) ^ srow)) * 8;  // swizzled source chunk
    const int sw   = (l15 & 7);            // read-side row swizzle key

    auto stage = [&](int buf, int k0) {
        unsigned short* As  = smem[buf];
        unsigned short* Bqs = smem[buf] + 8192;
        unsigned short* Bks = smem[buf] + 12288;
        unsigned short* Bvs = smem[buf] + 16384;
        #pragma unroll
        for (int c = 0; c < 4; c++) {
            int r = c * 32 + wave * 8 + srow;
            gload16(Ap + (size_t)r * 1024 + k0 + swz, &As[r * 64 + ch8]);
        }
        #pragma unroll
        for (int c = 0; c < 2; c++) {
            int r = c * 32 + wave * 8 + srow;
            gload16(Bqp + (size_t)r * 1024 + k0 + swz, &Bqs[r * 64 + ch8]);
            gload16(Bkp + (size_t)r * 1024 + k0 + swz, &Bks[r * 64 + ch8]);
            gload16(Bvp + (size_t)r * 1024 + k0 + swz, &Bvs[r * 64 + ch8]);
        }
    };

    stage(0, 0);
    int cur = 0;
    for (int k0 = 0; k0 < 1024; k0 += 64) {
        VMCNT(0);      // tile(k0)'s 10 loads (issued last iter) landed
        LGKMCNT0();    // my ds_reads of buf cur^1 (last iter's compute) done
        BARRIER();     // all waves ditto; tile(k0) LDS-visible block-wide
        if (k0 + 64 < 1024)
            stage(cur ^ 1, k0 + 64);   // prefetch under this iter's compute
        const unsigned short* As  = smem[cur];
        const unsigned short* Bqs = smem[cur] + 8192;
        const unsigned short* Bks = smem[cur] + 12288;
        const unsigned short* Bvs = smem[cur] + 16384;
        #pragma unroll
        for (int kk = 0; kk < 2; kk++) {
            bf16x8 af[4], bqf[2], bkf[2], bvf[2];
            const int co = (((kk * 4 + quad) ^ sw)) * 8;
            #pragma unroll
            for (int i = 0; i < 4; i++)
                af[i] = *(const bf16x8*)&As[(wrow + i * 16 + l15) * 64 + co];
            #pragma unroll
            for (int j = 0; j < 2; j++) {
                bqf[j] = *(const bf16x8*)&Bqs[(wcol + j * 16 + l15) * 64 + co];
                bkf[j] = *(const bf16x8*)&Bks[(wcol + j * 16 + l15) * 64 + co];
                bvf[j] = *(const bf16x8*)&Bvs[(wcol + j * 16 + l15) * 64 + co];
            }
            #pragma unroll
            for (int i = 0; i < 4; i++)
                #pragma unroll
                for (int j = 0; j < 2; j++) {
                    aq[i][j] = __builtin_amdgcn_mfma_f32_16x16x32_bf16(
                        af[i], bqf[j], aq[i][j], 0, 0, 0);
                    ak[i][j] = __builtin_amdgcn_mfma_f32_16x16x32_bf16(
                        af[i], bkf[j], ak[i][j], 0, 0, 0);
                    av[i][j] = __builtin_amdgcn_mfma_f32_16x16x32_bf16(
                        af[i], bvf[j], av[i][j], 0, 0, 0);
                }
        }
        cur ^= 1;
    }

    // Q/K epilogue (registers only). C/D: col=lane&15, row=quad*4+reg.
    #pragma unroll
    for (int j = 0; j < 2; j++) {
        int col = y0 + wcol + j * 16 + l15;
        float bqc = bq[col], bkc = bk[col];
        int h = col >> 6, d = col & 63;
        #pragma unroll
        for (int i = 0; i < 4; i++)
            #pragma unroll
            for (int r = 0; r < 4; r++) {
                int row = x0 + wrow + i * 16 + quad * 4 + r;
                int b = row >> 11, s = row & 2047;
                size_t idx = (size_t)((b * 16 + h) * 2048 + s) * 64 + d;
                Qb[idx] = f2bf((aq[i][j][r] + bqc) * QSCALE);
                Kb[idx] = f2bf(ak[i][j][r] + bkc);
            }
    }

    // V epilogue: transpose through LDS, then coalesced V^T stores.
    __syncthreads();                        // staging smem now free
    unsigned short* vts = smem[0];          // 64 x 136 shorts (17.4 KB)
    #pragma unroll
    for (int j = 0; j < 2; j++) {
        int n = wcol + j * 16 + l15;        // 0..63 (d within tile)
        float bvc = bv[y0 + n];
        #pragma unroll
        for (int i = 0; i < 4; i++)
            #pragma unroll
            for (int r = 0; r < 4; r++) {
                int m = wrow + i * 16 + quad * 4 + r;   // 0..127 (seq in tile)
                vts[n * 136 + m] = f2bf(av[i][j][r] + bvc);
            }
    }
    __syncthreads();
    const int bseq = x0 >> 11;
    const int s0 = x0 & 2047;
    #pragma unroll
    for (int q = 0; q < 4; q++) {
        int c = q * 256 + tid;              // 0..1023 chunks of 16B
        int n = c >> 4, mc = c & 15;
        uint4 vv = *(const uint4*)&vts[n * 136 + mc * 8];
        *(uint4*)&Vt[(size_t)(bseq * 1024 + y0 + n) * 2048 + s0 + mc * 8] = vv;
    }
}

// ---------------- flash attention (fixed-max, split-T) ---------------------
// 128 Q rows/block, 4 waves x 32 rows (mi=2). l via MFMA ones-column.
// Register-P: swapped QK (mfma(K,Q)) + bit-permuted K staging puts P directly
// into PV A-fragment lanes; v_cvt_pk_bf16_f32 packs C-regs -> A-frags.
// K/V double-buffered (32.8 KB LDS -> 4 blocks/CU), counted prefetch with a
// SINGLE barrier per tile-iter: VMCNT(0); lgkm(0); barrier; stage(next);
// compute. (R4 form — best measured: 45.9 us, VGPR 64.)
__global__ __launch_bounds__(256) void attn_kernel(
    const unsigned short* __restrict__ Qb, const unsigned short* __restrict__ Kb,
    const unsigned short* __restrict__ Vt, unsigned short* __restrict__ Cc,
    float* __restrict__ Op, float* __restrict__ Lp, int tlen, int do_split) {
    const int bh = blockIdx.y;            // 0..31
    const int b = bh >> 4, h = bh & 15;
    const int q0 = blockIdx.x * 128;
    const int split = blockIdx.z;
    const int tbeg = split * tlen;

    const int tid = threadIdx.x;
    const int lane = tid & 63, wave = tid >> 6;
    const int quad = lane >> 4, l15 = lane & 15;

    __shared__ __align__(16) unsigned short Ks[2][64 * 64];
    __shared__ __align__(16) unsigned short Vs[2][64 * 64];

    const unsigned short* Qbh = Qb + (size_t)bh * 2048 * 64;
    const unsigned short* Kbh = Kb + (size_t)bh * 2048 * 64;
    const unsigned short* Vbh = Vt + (size_t)bh * 64 * 2048;

    // Q fragments in registers: B-operand layout n=lane&15, k=quad*8+j
    bf16x8 qa[2][2];
    #pragma unroll
    for (int mi = 0; mi < 2; mi++)
        #pragma unroll
        for (int kk = 0; kk < 2; kk++)
            qa[mi][kk] = *(const bf16x8*)&Qbh[
                (size_t)(q0 + wave * 32 + mi * 16 + l15) * 64 + kk * 32 + quad * 8];

    union { unsigned short us[8]; bf16x8 v; } ones_u;
    #pragma unroll
    for (int i = 0; i < 8; i++) ones_u.us[i] = 0x3F80;
    const bf16x8 onesv = ones_u.v;

    f32x4 o[2][4] = {};
    f32x4 ol[2] = {};

    const int srow = lane >> 3;                 // 0..7
    const int r0s = wave * 16 + srow;           // staging rows (2 per lane)
    const int ch8 = (lane & 7) * 8;
    const int swz = (((lane & 7) ^ srow)) * 8;  // row&7 == srow for both rows
    const int sw  = (l15 & 7);

    // K row bit-permutation: LDS row t' holds global K row perm(t'), with
    // t' = [kk jl q1 q0 r1 r0] <- t = [kk q1 q0 jl r1 r0]. This makes the
    // PV A-fragment k-slot equal NATURAL t (V stays unpermuted).
    const int pk0 = (r0s & 0x23) | ((r0s & 0x0C) << 1) | ((r0s & 0x10) >> 2);
    const int r8  = r0s + 8;
    const int pk8 = (r8 & 0x23) | ((r8 & 0x0C) << 1) | ((r8 & 0x10) >> 2);

    auto stage = [&](int buf, int t0) {
        gload16(&Kbh[(size_t)(t0 + pk0) * 64 + swz],       &Ks[buf][r0s * 64 + ch8]);
        gload16(&Kbh[(size_t)(t0 + pk8) * 64 + swz],       &Ks[buf][(r0s + 8) * 64 + ch8]);
        gload16(&Vbh[(size_t)r0s * 2048 + t0 + swz],       &Vs[buf][r0s * 64 + ch8]);
        gload16(&Vbh[(size_t)(r0s + 8) * 2048 + t0 + swz], &Vs[buf][(r0s + 8) * 64 + ch8]);
    };

    stage(0, tbeg);
    int cur = 0;
    for (int ti = 0; ti < tlen; ti += 64) {
        // Tile i's 4 loads are the only outstanding vmem -> VMCNT(0) is exact.
        VMCNT(0);
        LGKMCNT0();    // my ds_reads of tile i-1 (buf cur^1) complete
        BARRIER();     // all waves ditto + tile i LDS-visible
        if (ti + 64 < tlen)
            stage(cur ^ 1, tbeg + ti + 64);  // prefetch next K/V tile
        const unsigned short* Ksc = Ks[cur];
        const unsigned short* Vsc = Vs[cur];

        // S^T = K Q^T (log2 domain): A=K, B=Q. q lands on l15 lane.
        f32x4 sf[2][4] = {};
        #pragma unroll
        for (int j = 0; j < 4; j++)
            #pragma unroll
            for (int kk = 0; kk < 2; kk++) {
                bf16x8 kf = *(const bf16x8*)&Ksc[(j * 16 + l15) * 64 +
                                                 (((kk * 4 + quad) ^ sw)) * 8];
                sf[0][j] = __builtin_amdgcn_mfma_f32_16x16x32_bf16(kf, qa[0][kk], sf[0][j], 0, 0, 0);
                sf[1][j] = __builtin_amdgcn_mfma_f32_16x16x32_bf16(kf, qa[1][kk], sf[1][j], 0, 0, 0);
            }

        // P = exp2(S^T); pack into PV A-fragments entirely in registers.
        // pa[mi][kk] dword d = cvt_pk(p[2kk+(d>>1)][2(d&1)], p[..][2(d&1)+1]):
        // A-frag k = kk*32 + quad*8 + e == natural t by K-staging design.
        union { unsigned int u[4]; bf16x8 v; } pa[2][2];
        #pragma unroll
        for (int mi = 0; mi < 2; mi++) {
            float pe[4][4];
            #pragma unroll
            for (int j = 0; j < 4; j++)
                #pragma unroll
                for (int r = 0; r < 4; r++)
                    pe[j][r] = EXPFN(sf[mi][j][r]);
            #pragma unroll
            for (int kk = 0; kk < 2; kk++)
                #pragma unroll
                for (int d = 0; d < 4; d++) {
                    const int j = 2 * kk + (d >> 1);
                    const int r = 2 * (d & 1);
                    unsigned int w;
                    asm("v_cvt_pk_bf16_f32 %0, %1, %2"
                        : "=v"(w) : "v"(pe[j][r]), "v"(pe[j][r + 1]));
                    pa[mi][kk].u[d] = w;
                }
        }

        // O += P V ; l += P @ ones  (vf shared across mi)
        #pragma unroll
        for (int kk = 0; kk < 2; kk++) {
            bf16x8 pf0 = pa[0][kk].v;
            bf16x8 pf1 = pa[1][kk].v;
            ol[0] = __builtin_amdgcn_mfma_f32_16x16x32_bf16(pf0, onesv, ol[0], 0, 0, 0);
            ol[1] = __builtin_amdgcn_mfma_f32_16x16x32_bf16(pf1, onesv, ol[1], 0, 0, 0);
            #pragma unroll
            for (int j = 0; j < 4; j++) {
                bf16x8 vf = *(const bf16x8*)&Vsc[(j * 16 + l15) * 64 +
                                                 (((kk * 4 + quad) ^ sw)) * 8];
                o[0][j] = __builtin_amdgcn_mfma_f32_16x16x32_bf16(pf0, vf, o[0][j], 0, 0, 0);
                o[1][j] = __builtin_amdgcn_mfma_f32_16x16x32_bf16(pf1, vf, o[1][j], 0, 0, 0);
            }
        }
        cur ^= 1;
    }

    if (do_split) {
        float* Opd = Op + (size_t)(split * 32 + bh) * 2048 * 64;
        float* Lpd = Lp + (size_t)(split * 32 + bh) * 2048;
        #pragma unroll
        for (int mi = 0; mi < 2; mi++)
            #pragma unroll
            for (int r = 0; r < 4; r++) {
                int s = q0 + wave * 32 + mi * 16 + quad * 4 + r;
                if (l15 == 0) Lpd[s] = ol[mi][r];
                #pragma unroll
                for (int j = 0; j < 4; j++)
                    Opd[(size_t)s * 64 + j * 16 + l15] = o[mi][j][r];
            }
    } else {
        #pragma unroll
        for (int mi = 0; mi < 2; mi++)
            #pragma unroll
            for (int r = 0; r < 4; r++) {
                float inv = 1.f / ol[mi][r];
                int s = q0 + wave * 32 + mi * 16 + quad * 4 + r;
                size_t row = (size_t)(b * 2048 + s);
                #pragma unroll
                for (int j = 0; j < 4; j++)
                    Cc[row * 1024 + h * 64 + j * 16 + l15] = f2bf(o[mi][j][r] * inv);
            }
    }
}

// ---------------- combine split partials -> Cc bf16 ------------------------
__global__ __launch_bounds__(256) void combine_kernel(
    const float4* __restrict__ Op, const float* __restrict__ Lp,
    unsigned short* __restrict__ Cc) {
    int idx = blockIdx.x * 256 + threadIdx.x;       // 0 .. 32*2048*16-1
    int d4 = idx & 15;
    int s = (idx >> 4) & 2047;
    int bh = idx >> 15;
    const size_t half4 = (size_t)32 * 2048 * 16;
    float4 a = Op[(size_t)idx], c = Op[half4 + (size_t)idx];
    float l = Lp[bh * 2048 + s] + Lp[32 * 2048 + bh * 2048 + s];
    float inv = 1.f / l;
    ushort4 o;
    o.x = f2bf((a.x + c.x) * inv); o.y = f2bf((a.y + c.y) * inv);
    o.z = f2bf((a.z + c.z) * inv); o.w = f2bf((a.w + c.w) * inv);
    int b = bh >> 4, h = bh & 15;
    *(ushort4*)&Cc[((size_t)(b * 2048 + s)) * 1024 + h * 64 + d4 * 4] = o;
}

// ---------------- output projection (128x64 tile, double-buffer) -----------
// grid (32,16) = 512 blocks = 2/CU (grid cap); LDS 48 KB (3/CU capacity, no
// loss); single-barrier counted prefetch as qkv.
__global__ __launch_bounds__(256) void gemm_out_kernel(
    const unsigned short* __restrict__ Cc, const unsigned short* __restrict__ Wot,
    const float* __restrict__ bo, float* __restrict__ out) {
    const int m0 = blockIdx.x * 128;   // over 4096
    const int n0 = blockIdx.y * 64;    // over 1024

    __shared__ __align__(16) unsigned short As[2][128 * 64];
    __shared__ __align__(16) unsigned short Bs[2][64 * 64];

    const int tid = threadIdx.x;
    const int lane = tid & 63, wave = tid >> 6;
    const int quad = lane >> 4, l15 = lane & 15;
    const int wrow = (wave >> 1) * 64, wcol = (wave & 1) * 32;

    f32x4 acc[4][2] = {};
    const int srow = lane >> 3;
    const int ch8 = (lane & 7) * 8;
    const int swz = (((lane & 7) ^ srow)) * 8;
    const int sw  = (l15 & 7);

    auto stage = [&](int buf, int k0) {
        #pragma unroll
        for (int c = 0; c < 4; c++) {
            int r = c * 32 + wave * 8 + srow;
            gload16(Cc + (size_t)(m0 + r) * 1024 + k0 + swz, &As[buf][r * 64 + ch8]);
            if (c < 2)
                gload16(Wot + (size_t)(n0 + r) * 1024 + k0 + swz, &Bs[buf][r * 64 + ch8]);
        }
    };

    stage(0, 0);
    int cur = 0;
    for (int k0 = 0; k0 < 1024; k0 += 64) {
        VMCNT(0);      // tile(k0)'s 6 loads landed
        LGKMCNT0();    // my ds_reads of buf cur^1 done
        BARRIER();
        if (k0 + 64 < 1024)
            stage(cur ^ 1, k0 + 64);
        #pragma unroll
        for (int kk = 0; kk < 2; kk++) {
            bf16x8 af[4], bfr[2];
            #pragma unroll
            for (int i = 0; i < 4; i++)
                af[i] = *(const bf16x8*)&As[cur][(wrow + i * 16 + l15) * 64 +
                                                 (((kk * 4 + quad) ^ sw)) * 8];
            #pragma unroll
            for (int j = 0; j < 2; j++)
                bfr[j] = *(const bf16x8*)&Bs[cur][(wcol + j * 16 + l15) * 64 +
                                                  (((kk * 4 + quad) ^ sw)) * 8];
            #pragma unroll
            for (int i = 0; i < 4; i++)
                #pragma unroll
                for (int j = 0; j < 2; j++)
                    acc[i][j] = __builtin_amdgcn_mfma_f32_16x16x32_bf16(
                        af[i], bfr[j], acc[i][j], 0, 0, 0);
        }
        cur ^= 1;
    }

    #pragma unroll
    for (int j = 0; j < 2; j++) {
        int col = n0 + wcol + j * 16 + l15;
        float bcol = bo[col];
        #pragma unroll
        for (int i = 0; i < 4; i++)
            #pragma unroll
            for (int r = 0; r < 4; r++) {
                int row = m0 + wrow + i * 16 + quad * 4 + r;
                out[(size_t)row * 1024 + col] = acc[i][j][r] + bcol;
            }
    }
}

// ---------------------------------------------------------------------------
extern "C" void kernel_launch(void* const* d_in, const int* in_sizes, int n_in,
                              void* d_out, int out_size, void* d_ws, size_t ws_size,
                              hipStream_t stream) {
    const float* X  = (const float*)d_in[0];
    const float* Wq = (const float*)d_in[1];
    const float* bq = (const float*)d_in[2];
    const float* Wk = (const float*)d_in[3];
    const float* bk = (const float*)d_in[4];
    const float* Wv = (const float*)d_in[5];
    const float* bv = (const float*)d_in[6];
    const float* Wo = (const float*)d_in[7];
    const float* bo = (const float*)d_in[8];
    float* out = (float*)d_out;

    char* ws = (char*)d_ws;
    unsigned short* Xb = (unsigned short*)(ws);                    //  8 MB
    unsigned short* Wt = (unsigned short*)(ws + (8u  << 20));      //  8 MB (4 mats)
    unsigned short* Qb = (unsigned short*)(ws + (16u << 20));      //  8 MB
    unsigned short* Kb = (unsigned short*)(ws + (24u << 20));      //  8 MB
    unsigned short* Vt = (unsigned short*)(ws + (32u << 20));      //  8 MB
    unsigned short* Cc = (unsigned short*)(ws + (40u << 20));      //  8 MB
    float* Op = (float*)(ws + (48u << 20));                        // 32 MB
    float* Lp = (float*)(ws + (48u << 20) + 33554432u);            // 512 KB
    const bool use_split = ws_size >= ((size_t)(48u << 20) + 33554432u + 524288u);

    prep_kernel<<<dim3(32, 32, 5), 256, 0, stream>>>(X, (ushort4*)Xb, Wq, Wk, Wv, Wo, Wt);
    gemm_qkv_kernel<<<dim3(32, 16), 256, 0, stream>>>(Xb, Wt, bq, bk, bv, Qb, Kb, Vt);
    if (use_split) {
        attn_kernel<<<dim3(16, 32, 2), 256, 0, stream>>>(Qb, Kb, Vt, Cc, Op, Lp, 1024, 1);
        combine_kernel<<<4096, 256, 0, stream>>>((const float4*)Op, Lp, Cc);
    } else {
        attn_kernel<<<dim3(16, 32, 1), 256, 0, stream>>>(Qb, Kb, Vt, Cc, Op, Lp, 2048, 0);
    }
    gemm_out_kernel<<<dim3(32, 16), 256, 0, stream>>>(Cc, Wt + 3u * 1024 * 1024, bo, out);
}